// Round 4
// baseline (56.830 us; speedup 1.0000x reference)
//
#include <hip/hip_runtime.h>
#include <math.h>

// Problem constants (fixed by the reference)
constexpr int B_    = 8;
constexpr int CIN_  = 128;
constexpr int H_    = 28;
constexpr int W_    = 28;
constexpr int COUT_ = 256;
constexpr int OH_   = 28;
constexpr int OW_   = 28;
constexpr int L_    = OH_ * OW_;     // 784
constexpr int N_    = B_ * L_;       // 6272
constexpr int NCB_  = 64;
constexpr int K_    = 16;
constexpr int SUB_  = 18;            // 2 channels x 9 taps

typedef short v4s __attribute__((ext_vector_type(4)));

// ws layout (byte offsets)
constexpr size_t WS_IDXT = 0;                          // N_*64 uchar = 401408 B
constexpr size_t WS_LUT  = 1u << 20;                   // 262144 int16 = 512 KB
constexpr size_t WS_CFT  = (1u << 20) + (768u << 10);  // 64*18*16 f32 = 73728 B
constexpr size_t WS_Y2   = WS_CFT + (128u << 10);      // 1024 f32
constexpr size_t WS_BF   = WS_Y2  + (16u << 10);       // 256 f32

// ---------------------------------------------------------------------------
// Pre-pass: LUT int32->int16; centroids -> k-major float(c_q - c_z);
// y2 integer (double) -> f32; bias -> dequantized f32.
// ---------------------------------------------------------------------------
__global__ __launch_bounds__(256) void amm_pack(
    const int* __restrict__ lut_q,
    const int* __restrict__ c_q, const float* __restrict__ c_s,
    const int* __restrict__ c_z, const float* __restrict__ x_s,
    const int* __restrict__ bias_q, const float* __restrict__ bias_s,
    const int* __restrict__ bias_z,
    short* __restrict__ lut16, float* __restrict__ cft,
    float* __restrict__ y2f, float* __restrict__ biasf)
{
    const int bid = blockIdx.x, tid = threadIdx.x;
    if (bid < 256) {
        const int i = bid * 1024 + tid * 4;      // covers 262144 exactly
        const int4 v = *(const int4*)(lut_q + i);
        v4s o; o.x = (short)v.x; o.y = (short)v.y; o.z = (short)v.z; o.w = (short)v.w;
        *(v4s*)(lut16 + i) = o;
    } else if (bid < 260) {
        const int t = (bid - 256) * 256 + tid;   // (cb,k) pair, 1024 total
        if (t >= NCB_ * K_) return;
        const int cb = t >> 4, k = t & 15;
        const int zc = c_z[cb];
        const double csf = (double)c_s[cb];
        const double den = (double)x_s[0] * csf;
        double s2 = 0.0;
        for (int s = 0; s < SUB_; ++s) {
            const int ci = c_q[t * SUB_ + s] - zc;
            cft[(cb * SUB_ + s) * 16 + k] = (float)ci;   // exact small int
            const double d = (double)ci * csf;
            s2 += d * d;
        }
        y2f[t] = (float)(int)rint(s2 / den);     // < 2^24 -> exact in f32
    } else {
        biasf[tid] = (float)(bias_q[tid] - bias_z[0]) * bias_s[0];
    }
}

// ---------------------------------------------------------------------------
// Phase 1: per (codebook, position) argmin over 16 centroids.
// dist = y2[k] - 2*dot; dot exact integer in f32. Centroids k-major, block-
// uniform address -> s_load_dwordx16 per s. Output: transposed bytes
// idx_t[n*64 + cb].
// ---------------------------------------------------------------------------
__global__ __launch_bounds__(256) void amm_phase1(
    const int* __restrict__ x_q, const int* __restrict__ x_z,
    const float* __restrict__ cft, const float* __restrict__ y2f,
    unsigned char* __restrict__ idx_t)
{
    const int cb  = blockIdx.x;
    const int tid = threadIdx.x;
    const int n   = blockIdx.y * 256 + tid;
    if (n >= N_) return;

    const float* __restrict__ crow = cft + cb * (SUB_ * 16);  // [s][k]
    const float* __restrict__ yrow = y2f + cb * K_;

    const int xz = x_z[0];
    const int b  = n / L_;
    const int r  = n - b * L_;
    const int oh = r / OW_;
    const int ow = r - oh * OW_;

    float xi[SUB_];
    #pragma unroll
    for (int c2 = 0; c2 < 2; ++c2) {
        const int* base = x_q + (size_t)(b * CIN_ + 2 * cb + c2) * (H_ * W_);
        #pragma unroll
        for (int kh = 0; kh < 3; ++kh) {
            const int h = oh + kh - 1;
            #pragma unroll
            for (int kw = 0; kw < 3; ++kw) {
                const int w = ow + kw - 1;
                int v = 0;
                if ((unsigned)h < (unsigned)H_ && (unsigned)w < (unsigned)W_)
                    v = base[h * W_ + w] - xz;
                xi[c2 * 9 + kh * 3 + kw] = (float)v;
            }
        }
    }

    float dot[K_];
    #pragma unroll
    for (int k = 0; k < K_; ++k) dot[k] = 0.0f;
    #pragma unroll
    for (int s = 0; s < SUB_; ++s) {
        const float xs = xi[s];
        #pragma unroll
        for (int k = 0; k < K_; ++k)
            dot[k] = fmaf(xs, crow[s * 16 + k], dot[k]);
    }

    float bestd = 3.0e38f;
    int   bestk = 0;
    #pragma unroll
    for (int k = 0; k < K_; ++k) {
        const float d = fmaf(-2.0f, dot[k], yrow[k]);  // exact integer-valued
        if (d < bestd) { bestd = d; bestk = k; }       // strict < => first min
    }
    idx_t[(size_t)n * 64 + cb] = (unsigned char)bestk;
}

// ---------------------------------------------------------------------------
// Phase 2: block = 16 consecutive positions x 256 couts (grid 392).
// Gather: wave w handles pos w*4..w*4+3; per pos, 64 scalar idx bytes ->
// wave-uniform LUT row base; v4s loads co-across-lanes; pk_add_i16 acc.
// Epilogue: LDS transpose, then stores with 16 consecutive r per 16-lane
// group = full 64B lines (coalesced).
// ---------------------------------------------------------------------------
__global__ __launch_bounds__(256) void amm_phase2(
    const unsigned char* __restrict__ idx_t, const short* __restrict__ lut16,
    const float* __restrict__ lut_s, const int* __restrict__ lut_z,
    const float* __restrict__ biasf,
    const float* __restrict__ out_s, const int* __restrict__ out_z,
    int* __restrict__ out)
{
    const int tid  = threadIdx.x;
    const int lane = tid & 63;
    const int w    = __builtin_amdgcn_readfirstlane(tid >> 6);
    const int nb   = blockIdx.x * 16;
    const int b    = nb / L_;          // uniform; 784%16==0 so no b crossing
    const int r0   = nb - b * L_;

    __shared__ unsigned int res[16][132];  // [pos][128 u32 (=2 couts each) +pad]

    #pragma unroll
    for (int p = 0; p < 4; ++p) {
        const int pos = w * 4 + p;
        const unsigned int* rowp =
            (const unsigned int*)(idx_t + (size_t)(nb + pos) * 64);
        v4s acc = {0, 0, 0, 0};
        #pragma unroll
        for (int cw = 0; cw < 16; ++cw) {
            const unsigned int word = rowp[cw];
            #pragma unroll
            for (int j = 0; j < 4; ++j) {
                const int cb = cw * 4 + j;
                const int k  = (word >> (8 * j)) & 0xff;
                acc += *(const v4s*)((const char*)lut16 +
                        ((size_t)((cb << 4) + k) << 9) + (lane << 3));
            }
        }
        union { v4s s; unsigned int u[2]; } cv; cv.s = acc;
        res[pos][lane * 2]     = cv.u[0];  // couts 4*lane, 4*lane+1
        res[pos][lane * 2 + 1] = cv.u[1];  // couts 4*lane+2, 4*lane+3
    }
    __syncthreads();

    const float lsf = lut_s[0];
    const int   lz  = lut_z[0];
    const float osf = out_s[0];
    const float ozf = (float)out_z[0];

    const int pos   = tid & 15;
    const int ug    = tid >> 4;
    const int rbase = r0 + pos;

    #pragma unroll
    for (int ui = 0; ui < 8; ++ui) {
        const int u = ug * 8 + ui;
        const unsigned int vv = res[pos][u];
        const int co0 = u * 2, co1 = co0 + 1;
        const int s0 = (int)(short)(vv & 0xffff);
        const int s1 = (int)(short)(vv >> 16);

        float f0 = (float)(s0 - NCB_ * lz) * lsf + biasf[co0];
        float f1 = (float)(s1 - NCB_ * lz) * lsf + biasf[co1];
        f0 = fmaxf(f0, 0.0f) / osf + ozf;
        f1 = fmaxf(f1, 0.0f) / osf + ozf;
        f0 = fminf(fmaxf(f0, -128.0f), 127.0f);
        f1 = fminf(fmaxf(f1, -128.0f), 127.0f);
        out[(size_t)(b * COUT_ + co0) * L_ + rbase] = (int)rintf(f0);
        out[(size_t)(b * COUT_ + co1) * L_ + rbase] = (int)rintf(f1);
    }
}

extern "C" void kernel_launch(void* const* d_in, const int* in_sizes, int n_in,
                              void* d_out, int out_size, void* d_ws, size_t ws_size,
                              hipStream_t stream)
{
    const int*   x_q    = (const int*)  d_in[0];
    const float* x_s    = (const float*)d_in[1];
    const int*   x_z    = (const int*)  d_in[2];
    const int*   c_q    = (const int*)  d_in[3];
    const float* c_s    = (const float*)d_in[4];
    const int*   c_z    = (const int*)  d_in[5];
    const int*   lut_q  = (const int*)  d_in[6];
    const float* lut_s  = (const float*)d_in[7];
    const int*   lut_z  = (const int*)  d_in[8];
    const int*   bias_q = (const int*)  d_in[9];
    const float* bias_s = (const float*)d_in[10];
    const int*   bias_z = (const int*)  d_in[11];
    const float* out_s  = (const float*)d_in[12];
    const int*   out_z  = (const int*)  d_in[13];

    char* ws = (char*)d_ws;
    unsigned char* idx_t = (unsigned char*)(ws + WS_IDXT);
    short* lut16  = (short*)(ws + WS_LUT);
    float* cft    = (float*)(ws + WS_CFT);
    float* y2fp   = (float*)(ws + WS_Y2);
    float* biasf  = (float*)(ws + WS_BF);

    amm_pack<<<dim3(261), 256, 0, stream>>>(lut_q, c_q, c_s, c_z, x_s,
                                            bias_q, bias_s, bias_z,
                                            lut16, cft, y2fp, biasf);

    dim3 g1(NCB_, (N_ + 255) / 256);
    amm_phase1<<<g1, 256, 0, stream>>>(x_q, x_z, cft, y2fp, idx_t);

    amm_phase2<<<dim3(N_ / 16), 256, 0, stream>>>(
        idx_t, lut16, lut_s, lut_z, biasf, out_s, out_z, (int*)d_out);
}

// Round 5
// 37.896 us; speedup vs baseline: 1.4996x; 1.4996x over previous
//
#include <hip/hip_runtime.h>
#include <math.h>

// Problem constants (fixed by the reference)
constexpr int B_    = 8;
constexpr int CIN_  = 128;
constexpr int H_    = 28;
constexpr int W_    = 28;
constexpr int COUT_ = 256;
constexpr int OH_   = 28;
constexpr int OW_   = 28;
constexpr int L_    = OH_ * OW_;     // 784
constexpr int N_    = B_ * L_;       // 6272
constexpr int NCB_  = 64;
constexpr int K_    = 16;
constexpr int SUB_  = 18;            // 2 channels x 9 taps

typedef short v4s __attribute__((ext_vector_type(4)));

// ws layout (byte offsets)
constexpr size_t WS_IDXT = 0;                          // N_*64 uchar = 401408 B
constexpr size_t WS_LUT  = 1u << 20;                   // 262144 int16 = 512 KB
constexpr size_t WS_CFT  = (1u << 20) + (768u << 10);  // 64*18*16 f32 = 73728 B
constexpr size_t WS_Y2   = WS_CFT + (128u << 10);      // 1024 f32
constexpr size_t WS_BF   = WS_Y2  + (16u << 10);       // 256 f32

// ---------------------------------------------------------------------------
// Pre-pass: LUT int32->int16; centroids -> k-major float(c_q - c_z);
// y2 integer (double) -> f32; bias -> dequantized f32.
// ---------------------------------------------------------------------------
__global__ __launch_bounds__(256) void amm_pack(
    const int* __restrict__ lut_q,
    const int* __restrict__ c_q, const float* __restrict__ c_s,
    const int* __restrict__ c_z, const float* __restrict__ x_s,
    const int* __restrict__ bias_q, const float* __restrict__ bias_s,
    const int* __restrict__ bias_z,
    short* __restrict__ lut16, float* __restrict__ cft,
    float* __restrict__ y2f, float* __restrict__ biasf)
{
    const int bid = blockIdx.x, tid = threadIdx.x;
    if (bid < 256) {
        const int i = bid * 1024 + tid * 4;      // covers 262144 exactly
        const int4 v = *(const int4*)(lut_q + i);
        v4s o; o.x = (short)v.x; o.y = (short)v.y; o.z = (short)v.z; o.w = (short)v.w;
        *(v4s*)(lut16 + i) = o;
    } else if (bid < 260) {
        const int t = (bid - 256) * 256 + tid;   // (cb,k) pair, 1024 total
        if (t >= NCB_ * K_) return;
        const int cb = t >> 4, k = t & 15;
        const int zc = c_z[cb];
        const double csf = (double)c_s[cb];
        const double den = (double)x_s[0] * csf;
        double s2 = 0.0;
        for (int s = 0; s < SUB_; ++s) {
            const int ci = c_q[t * SUB_ + s] - zc;
            cft[(cb * SUB_ + s) * 16 + k] = (float)ci;   // exact small int
            const double d = (double)ci * csf;
            s2 += d * d;
        }
        y2f[t] = (float)(int)rint(s2 / den);     // < 2^24 -> exact in f32
    } else {
        biasf[tid] = (float)(bias_q[tid] - bias_z[0]) * bias_s[0];
    }
}

// ---------------------------------------------------------------------------
// Phase 1: per (codebook, position) argmin over 16 centroids.
// dist = y2[k] - 2*dot; dot exact integer in f32. Centroids k-major, block-
// uniform address -> scalar loads. Output: transposed bytes idx_t[n*64+cb].
// ---------------------------------------------------------------------------
__global__ __launch_bounds__(256) void amm_phase1(
    const int* __restrict__ x_q, const int* __restrict__ x_z,
    const float* __restrict__ cft, const float* __restrict__ y2f,
    unsigned char* __restrict__ idx_t)
{
    const int cb  = blockIdx.x;
    const int tid = threadIdx.x;
    const int n   = blockIdx.y * 256 + tid;
    if (n >= N_) return;

    const float* __restrict__ crow = cft + cb * (SUB_ * 16);  // [s][k]
    const float* __restrict__ yrow = y2f + cb * K_;

    const int xz = x_z[0];
    const int b  = n / L_;
    const int r  = n - b * L_;
    const int oh = r / OW_;
    const int ow = r - oh * OW_;

    float xi[SUB_];
    #pragma unroll
    for (int c2 = 0; c2 < 2; ++c2) {
        const int* base = x_q + (size_t)(b * CIN_ + 2 * cb + c2) * (H_ * W_);
        #pragma unroll
        for (int kh = 0; kh < 3; ++kh) {
            const int h = oh + kh - 1;
            #pragma unroll
            for (int kw = 0; kw < 3; ++kw) {
                const int w = ow + kw - 1;
                int v = 0;
                if ((unsigned)h < (unsigned)H_ && (unsigned)w < (unsigned)W_)
                    v = base[h * W_ + w] - xz;
                xi[c2 * 9 + kh * 3 + kw] = (float)v;
            }
        }
    }

    float dot[K_];
    #pragma unroll
    for (int k = 0; k < K_; ++k) dot[k] = 0.0f;
    #pragma unroll
    for (int s = 0; s < SUB_; ++s) {
        const float xs = xi[s];
        #pragma unroll
        for (int k = 0; k < K_; ++k)
            dot[k] = fmaf(xs, crow[s * 16 + k], dot[k]);
    }

    float bestd = 3.0e38f;
    int   bestk = 0;
    #pragma unroll
    for (int k = 0; k < K_; ++k) {
        const float d = fmaf(-2.0f, dot[k], yrow[k]);  // exact integer-valued
        if (d < bestd) { bestd = d; bestk = k; }       // strict < => first min
    }
    idx_t[(size_t)n * 64 + cb] = (unsigned char)bestk;
}

// ---------------------------------------------------------------------------
// Phase 2: grid 1568 x 256 threads; each WAVE owns one position (4 pos/block).
// Gather restructured for ILP: 4 batches of 16 independent v4s loads into an
// explicit t[16] array (compiler must keep 16 loads in flight), then tree-add.
// Epilogue: LDS transpose; each thread owns one cout and writes an int4
// (4 consecutive r) = 16B segments.
// ---------------------------------------------------------------------------
__global__ __launch_bounds__(256, 4) void amm_phase2(
    const unsigned char* __restrict__ idx_t, const short* __restrict__ lut16,
    const float* __restrict__ lut_s, const int* __restrict__ lut_z,
    const float* __restrict__ biasf,
    const float* __restrict__ out_s, const int* __restrict__ out_z,
    int* __restrict__ out)
{
    const int tid  = threadIdx.x;
    const int lane = tid & 63;
    const int w    = __builtin_amdgcn_readfirstlane(tid >> 6);
    const int nb   = blockIdx.x * 4;
    const int b    = nb / L_;          // uniform; 784%4==0 so no b crossing
    const int r0   = nb - b * L_;
    const int pos  = w;                // wave id = position within block

    __shared__ unsigned int res[4][132];   // [pos][128 u32 = 256 couts] (+pad)

    // ---- gather: 64 LUT rows, batched 16 deep ----
    const uint4* rp = (const uint4*)(idx_t + (size_t)(nb + pos) * 64);
    v4s acc = {0, 0, 0, 0};
    #pragma unroll
    for (int bt = 0; bt < 4; ++bt) {
        const uint4 wq = rp[bt];
        const unsigned int wrd[4] = {wq.x, wq.y, wq.z, wq.w};
        v4s t[16];
        #pragma unroll
        for (int i = 0; i < 16; ++i) {
            const unsigned int k = (wrd[i >> 2] >> (8 * (i & 3))) & 0xffu;
            const int cb = bt * 16 + i;
            t[i] = *(const v4s*)((const char*)lut16 +
                    ((size_t)((cb << 4) + k) << 9) + (lane << 3));
        }
        // tree add (forces all 16 loads live before first use)
        #pragma unroll
        for (int st = 8; st >= 1; st >>= 1)
            #pragma unroll
            for (int i = 0; i < st; ++i) t[i] += t[i + st];
        acc += t[0];
    }

    union { v4s s; unsigned int u[2]; } cv; cv.s = acc;
    res[pos][lane * 2]     = cv.u[0];  // couts 4*lane, 4*lane+1
    res[pos][lane * 2 + 1] = cv.u[1];  // couts 4*lane+2, 4*lane+3
    __syncthreads();

    // ---- epilogue: thread t owns cout = t; int4 store of 4 consecutive r ----
    const float lsf = lut_s[0];
    const int   lz  = lut_z[0];
    const float osf = out_s[0];
    const float ozf = (float)out_z[0];

    const int co   = tid;
    const int u    = co >> 1;       // u32 index holding this cout
    const int half = co & 1;
    const float bf = biasf[co];

    int4 ov;
    int* ovp = (int*)&ov;
    #pragma unroll
    for (int p = 0; p < 4; ++p) {
        const unsigned int vv = res[p][u];
        const int sv = half ? (int)(short)(vv >> 16) : (int)(short)(vv & 0xffff);
        float f = (float)(sv - NCB_ * lz) * lsf + bf;
        f = fmaxf(f, 0.0f) / osf + ozf;
        f = fminf(fmaxf(f, -128.0f), 127.0f);
        ovp[p] = (int)rintf(f);
    }
    *(int4*)(out + (size_t)(b * COUT_ + co) * L_ + r0) = ov;
}

extern "C" void kernel_launch(void* const* d_in, const int* in_sizes, int n_in,
                              void* d_out, int out_size, void* d_ws, size_t ws_size,
                              hipStream_t stream)
{
    const int*   x_q    = (const int*)  d_in[0];
    const float* x_s    = (const float*)d_in[1];
    const int*   x_z    = (const int*)  d_in[2];
    const int*   c_q    = (const int*)  d_in[3];
    const float* c_s    = (const float*)d_in[4];
    const int*   c_z    = (const int*)  d_in[5];
    const int*   lut_q  = (const int*)  d_in[6];
    const float* lut_s  = (const float*)d_in[7];
    const int*   lut_z  = (const int*)  d_in[8];
    const int*   bias_q = (const int*)  d_in[9];
    const float* bias_s = (const float*)d_in[10];
    const int*   bias_z = (const int*)  d_in[11];
    const float* out_s  = (const float*)d_in[12];
    const int*   out_z  = (const int*)  d_in[13];

    char* ws = (char*)d_ws;
    unsigned char* idx_t = (unsigned char*)(ws + WS_IDXT);
    short* lut16  = (short*)(ws + WS_LUT);
    float* cft    = (float*)(ws + WS_CFT);
    float* y2fp   = (float*)(ws + WS_Y2);
    float* biasf  = (float*)(ws + WS_BF);

    amm_pack<<<dim3(261), 256, 0, stream>>>(lut_q, c_q, c_s, c_z, x_s,
                                            bias_q, bias_s, bias_z,
                                            lut16, cft, y2fp, biasf);

    dim3 g1(NCB_, (N_ + 255) / 256);
    amm_phase1<<<g1, 256, 0, stream>>>(x_q, x_z, cft, y2fp, idx_t);

    amm_phase2<<<dim3(N_ / 4), 256, 0, stream>>>(
        idx_t, lut16, lut_s, lut_z, biasf, out_s, out_z, (int*)d_out);
}

// Round 6
// 30.238 us; speedup vs baseline: 1.8794x; 1.2533x over previous
//
#include <hip/hip_runtime.h>
#include <math.h>

// Problem constants (fixed by the reference)
constexpr int B_    = 8;
constexpr int CIN_  = 128;
constexpr int H_    = 28;
constexpr int W_    = 28;
constexpr int COUT_ = 256;
constexpr int OH_   = 28;
constexpr int OW_   = 28;
constexpr int L_    = OH_ * OW_;     // 784
constexpr int N_    = B_ * L_;       // 6272
constexpr int NCB_  = 64;
constexpr int K_    = 16;
constexpr int SUB_  = 18;            // 2 channels x 9 taps

// ws layout (byte offsets)
constexpr size_t WS_IDXT = 0;                  // N_*64 uchar = 401408 B
constexpr size_t WS_LUT8 = 0x100000;           // 262144 uchar = 256 KB
constexpr size_t WS_CFT  = 0x180000;           // 64*18*16 f32 = 73728 B
constexpr size_t WS_Y2   = 0x1A0000;           // 1024 f32
constexpr size_t WS_BF2  = 0x1A8000;           // 256 f32 (bias + folded consts)

// ---------------------------------------------------------------------------
// Pre-pass: LUT int32 -> biased uint8 (v+128); centroids -> k-major
// float(c_q - c_z); y2 (double) -> f32; bias -> dequant f32 with the
// (8192 + 64*lut_z)*lut_s constant folded in.
// ---------------------------------------------------------------------------
__global__ __launch_bounds__(256) void amm_pack(
    const int* __restrict__ lut_q, const float* __restrict__ lut_s,
    const int* __restrict__ lut_z,
    const int* __restrict__ c_q, const float* __restrict__ c_s,
    const int* __restrict__ c_z, const float* __restrict__ x_s,
    const int* __restrict__ bias_q, const float* __restrict__ bias_s,
    const int* __restrict__ bias_z,
    unsigned char* __restrict__ lut8, float* __restrict__ cft,
    float* __restrict__ y2f, float* __restrict__ biasf2)
{
    const int bid = blockIdx.x, tid = threadIdx.x;
    if (bid < 256) {
        const int i = bid * 1024 + tid * 4;      // covers 262144 exactly
        const int4 v = *(const int4*)(lut_q + i);
        uchar4 o;
        o.x = (unsigned char)(v.x + 128);
        o.y = (unsigned char)(v.y + 128);
        o.z = (unsigned char)(v.z + 128);
        o.w = (unsigned char)(v.w + 128);
        *(uchar4*)(lut8 + i) = o;
    } else if (bid < 260) {
        const int t = (bid - 256) * 256 + tid;   // (cb,k) pair, 1024 total
        if (t >= NCB_ * K_) return;
        const int cb = t >> 4, k = t & 15;
        const int zc = c_z[cb];
        const double csf = (double)c_s[cb];
        const double den = (double)x_s[0] * csf;
        double s2 = 0.0;
        for (int s = 0; s < SUB_; ++s) {
            const int ci = c_q[t * SUB_ + s] - zc;
            cft[(cb * SUB_ + s) * 16 + k] = (float)ci;   // exact small int
            const double d = (double)ci * csf;
            s2 += d * d;
        }
        y2f[t] = (float)(int)rint(s2 / den);     // < 2^24 -> exact in f32
    } else {
        // biasf2[co] = dequant bias - (8192 + 64*lz)*ls   (folded constant)
        const double ls = (double)lut_s[0];
        const double c0 = (8192.0 + 64.0 * (double)lut_z[0]) * ls;
        biasf2[tid] = (float)((double)(bias_q[tid] - bias_z[0]) *
                              (double)bias_s[0] - c0);
    }
}

// ---------------------------------------------------------------------------
// Phase 1 (unchanged from R5): per (codebook, position) argmin over 16
// centroids. dist = y2[k] - 2*dot; dot exact integer in f32. Centroids
// k-major, block-uniform -> scalar loads. Output: bytes idx_t[n*64+cb].
// ---------------------------------------------------------------------------
__global__ __launch_bounds__(256) void amm_phase1(
    const int* __restrict__ x_q, const int* __restrict__ x_z,
    const float* __restrict__ cft, const float* __restrict__ y2f,
    unsigned char* __restrict__ idx_t)
{
    const int cb  = blockIdx.x;
    const int tid = threadIdx.x;
    const int n   = blockIdx.y * 256 + tid;
    if (n >= N_) return;

    const float* __restrict__ crow = cft + cb * (SUB_ * 16);  // [s][k]
    const float* __restrict__ yrow = y2f + cb * K_;

    const int xz = x_z[0];
    const int b  = n / L_;
    const int r  = n - b * L_;
    const int oh = r / OW_;
    const int ow = r - oh * OW_;

    float xi[SUB_];
    #pragma unroll
    for (int c2 = 0; c2 < 2; ++c2) {
        const int* base = x_q + (size_t)(b * CIN_ + 2 * cb + c2) * (H_ * W_);
        #pragma unroll
        for (int kh = 0; kh < 3; ++kh) {
            const int h = oh + kh - 1;
            #pragma unroll
            for (int kw = 0; kw < 3; ++kw) {
                const int w = ow + kw - 1;
                int v = 0;
                if ((unsigned)h < (unsigned)H_ && (unsigned)w < (unsigned)W_)
                    v = base[h * W_ + w] - xz;
                xi[c2 * 9 + kh * 3 + kw] = (float)v;
            }
        }
    }

    float dot[K_];
    #pragma unroll
    for (int k = 0; k < K_; ++k) dot[k] = 0.0f;
    #pragma unroll
    for (int s = 0; s < SUB_; ++s) {
        const float xs = xi[s];
        #pragma unroll
        for (int k = 0; k < K_; ++k)
            dot[k] = fmaf(xs, crow[s * 16 + k], dot[k]);
    }

    float bestd = 3.0e38f;
    int   bestk = 0;
    #pragma unroll
    for (int k = 0; k < K_; ++k) {
        const float d = fmaf(-2.0f, dot[k], yrow[k]);  // exact integer-valued
        if (d < bestd) { bestd = d; bestk = k; }       // strict < => first min
    }
    idx_t[(size_t)n * 64 + cb] = (unsigned char)bestk;
}

// ---------------------------------------------------------------------------
// Phase 2: grid 1568 x 256; each WAVE owns one position. Biased-uint8 LUT:
// per row one dword (4 couts) per lane; unpack via masks into two u32 accs
// of packed u16 sums (max 64*255 = 16320, carry-free with plain adds).
// 16-deep load batches for ILP. Epilogue: LDS transpose; thread co writes
// int4 (4 consecutive r).
// ---------------------------------------------------------------------------
__global__ __launch_bounds__(256, 6) void amm_phase2(
    const unsigned char* __restrict__ idx_t, const unsigned char* __restrict__ lut8,
    const float* __restrict__ lut_s, const float* __restrict__ biasf2,
    const float* __restrict__ out_s, const int* __restrict__ out_z,
    int* __restrict__ out)
{
    const int tid  = threadIdx.x;
    const int lane = tid & 63;
    const int w    = __builtin_amdgcn_readfirstlane(tid >> 6);
    const int nb   = blockIdx.x * 4;
    const int b    = nb / L_;          // uniform; 784%4==0 so no b crossing
    const int r0   = nb - b * L_;
    const int pos  = w;                // wave id = position within block

    __shared__ unsigned int res[4][130];   // [pos][128 words = 256 couts] +pad

    // prefetch full 64-B idx row (uniform address -> scalar loads)
    const uint4* rp = (const uint4*)(idx_t + (size_t)(nb + pos) * 64);
    uint4 q[4];
    q[0] = rp[0]; q[1] = rp[1]; q[2] = rp[2]; q[3] = rp[3];

    unsigned int accLo = 0, accHi = 0;   // packed u16 pairs
    #pragma unroll
    for (int bt = 0; bt < 4; ++bt) {
        const unsigned int wrd[4] = {q[bt].x, q[bt].y, q[bt].z, q[bt].w};
        unsigned int t[16];
        #pragma unroll
        for (int i = 0; i < 16; ++i) {
            const unsigned int k = (wrd[i >> 2] >> (8 * (i & 3))) & 0xffu;
            const int cb = bt * 16 + i;
            t[i] = *(const unsigned int*)(lut8 +
                    ((size_t)((cb << 4) + k) << 8) + (lane << 2));
        }
        #pragma unroll
        for (int i = 0; i < 16; ++i) {
            accLo += t[i] & 0x00FF00FFu;          // couts 4L, 4L+2
            accHi += (t[i] >> 8) & 0x00FF00FFu;   // couts 4L+1, 4L+3
        }
    }

    res[pos][lane * 2]     = accLo;
    res[pos][lane * 2 + 1] = accHi;
    __syncthreads();

    // ---- epilogue: thread t owns cout = t; int4 store of 4 consecutive r ----
    const float lsf = lut_s[0];
    const float osf = out_s[0];
    const float ozf = (float)out_z[0];

    const int co   = tid;
    const int c    = co & 3;
    const int u    = (co >> 2) * 2 + (c & 1);  // word index within row
    const int half = c >> 1;                   // u16 half within word
    const float bf = biasf2[co];

    int4 ov;
    int* ovp = (int*)&ov;
    #pragma unroll
    for (int p = 0; p < 4; ++p) {
        const unsigned int vv = res[p][u];
        const int sv = (int)((vv >> (16 * half)) & 0xffffu);
        float f = (float)sv * lsf + bf;        // = dequant sum + bias
        f = fmaxf(f, 0.0f) / osf + ozf;
        f = fminf(fmaxf(f, -128.0f), 127.0f);
        ovp[p] = (int)rintf(f);
    }
    *(int4*)(out + (size_t)(b * COUT_ + co) * L_ + r0) = ov;
}

extern "C" void kernel_launch(void* const* d_in, const int* in_sizes, int n_in,
                              void* d_out, int out_size, void* d_ws, size_t ws_size,
                              hipStream_t stream)
{
    const int*   x_q    = (const int*)  d_in[0];
    const float* x_s    = (const float*)d_in[1];
    const int*   x_z    = (const int*)  d_in[2];
    const int*   c_q    = (const int*)  d_in[3];
    const float* c_s    = (const float*)d_in[4];
    const int*   c_z    = (const int*)  d_in[5];
    const int*   lut_q  = (const int*)  d_in[6];
    const float* lut_s  = (const float*)d_in[7];
    const int*   lut_z  = (const int*)  d_in[8];
    const int*   bias_q = (const int*)  d_in[9];
    const float* bias_s = (const float*)d_in[10];
    const int*   bias_z = (const int*)  d_in[11];
    const float* out_s  = (const float*)d_in[12];
    const int*   out_z  = (const int*)  d_in[13];

    char* ws = (char*)d_ws;
    unsigned char* idx_t = (unsigned char*)(ws + WS_IDXT);
    unsigned char* lut8  = (unsigned char*)(ws + WS_LUT8);
    float* cft    = (float*)(ws + WS_CFT);
    float* y2fp   = (float*)(ws + WS_Y2);
    float* biasf2 = (float*)(ws + WS_BF2);

    amm_pack<<<dim3(261), 256, 0, stream>>>(lut_q, lut_s, lut_z,
                                            c_q, c_s, c_z, x_s,
                                            bias_q, bias_s, bias_z,
                                            lut8, cft, y2fp, biasf2);

    dim3 g1(NCB_, (N_ + 255) / 256);
    amm_phase1<<<g1, 256, 0, stream>>>(x_q, x_z, cft, y2fp, idx_t);

    amm_phase2<<<dim3(N_ / 4), 256, 0, stream>>>(
        idx_t, lut8, lut_s, biasf2, out_s, out_z, (int*)d_out);
}